// Round 6
// baseline (348.300 us; speedup 1.0000x reference)
//
#include <hip/hip_runtime.h>
#include <math.h>

#define NJ 17
#define NP 14
#define NCH 59         // 17 + 3*14
#define BATCH 256
#define NS (BATCH * NCH)   // 15104 slices
#define NWAVES 2048        // 512 blocks x 4 waves (2 blocks/CU x 256 CU)
#define PSTRIDE 64         // padded partial-row stride (floats)

__constant__ int c_par0[NP] = {0, 1, 2, 0, 4, 5, 0, 8, 14, 15, 8, 11, 12, 8};
__constant__ int c_par1[NP] = {1, 2, 3, 4, 5, 6, 8, 14, 15, 16, 11, 12, 13, 10};

__device__ __forceinline__ float wave_reduce(float v) {
    #pragma unroll
    for (int off = 32; off; off >>= 1) v += __shfl_down(v, off, 64);
    return v;
}

// Normalized heatmap h = exp(-0.25*(dx^2+dy^2-m)), m = d2 at clamped nearest
// integer grid point (== grid max of the gaussian, closed form).
__device__ __forceinline__ void heat_params(const float* __restrict__ joint2d,
                                            int b, int j,
                                            float& x, float& y, float& m) {
    x = joint2d[(b * NJ + j) * 2 + 0] * 64.f;
    y = joint2d[(b * NJ + j) * 2 + 1] * 64.f;
    const float rx = fminf(fmaxf(floorf(x + 0.5f), 0.f), 63.f);
    const float ry = fminf(fmaxf(floorf(y + 0.5f), 0.f), 63.f);
    m = (rx - x) * (rx - x) + (ry - y) * (ry - y);
}

// Persistent pipelined waves: 512 blocks x 4 waves; wave w grid-strides over
// slices sid = w, w+2048, ... Each iteration issues the NEXT slice's 16
// float4 loads (ping-pong named buffers) before computing the current one,
// so 16 KB/wave stays in flight continuously — no one-shot launch/drain gaps.
__global__ __launch_bounds__(256, 2) void slice_sum_kernel(
    const float* __restrict__ pred,     // [B,17,3]
    const float* __restrict__ joints,   // [B,17,3]
    const float* __restrict__ middle,   // [B,59,64,64]
    const float* __restrict__ joint2d,  // [B,17,2]
    float* __restrict__ partial)        // [B,PSTRIDE]: c=0..58 slices, 59=l3d
{
    const int lane = threadIdx.x & 63;
    const int w    = (blockIdx.x << 2) | (threadIdx.x >> 6);   // 0..2047

    float4 bufA[16], bufB[16];

    #define ISSUE(sid, buf)                                                    \
        {                                                                      \
            const float4* __restrict__ src =                                   \
                (const float4*)(middle + (size_t)(sid) * 4096) + lane;         \
            _Pragma("unroll")                                                  \
            for (int j = 0; j < 16; ++j) (buf)[j] = src[64 * j];               \
        }

    #define PROCESS(sid, buf)                                                  \
        {                                                                      \
            const int b = (sid) / NCH;                                         \
            const int c = (sid) - b * NCH;                                     \
            float wp = 0.f, wc = 0.f;                                          \
            int jp = 0, jc = 0;                                                \
            if (c < NJ) {                                                      \
                jp = c; wp = 1.f;                                              \
            } else {                                                           \
                const int pi = c - NJ;                                         \
                const int p  = pi / 3;                                         \
                const int ch = pi - p * 3;                                     \
                jp = c_par0[p];                                                \
                jc = c_par1[p];                                                \
                const float dz = joints[(b * NJ + jp) * 3 + 2] -               \
                                 joints[(b * NJ + jc) * 3 + 2];                \
                const int rs = (dz > 0.1f) ? 1 : ((fabsf(dz) < 0.1f) ? 0 : -1);\
                if (ch == 0)      { wp = 0.f; wc = (rs == -1) ? 1.f : 0.f; }   \
                else if (ch == 1) { wp = 1.f; wc = (rs ==  0) ? 1.f : 0.f; }   \
                else              { wp = 0.f; wc = (rs ==  1) ? 1.f : 0.f; }   \
            }                                                                  \
            float xp = 0.f, yp = 0.f, mp = 0.f;                                \
            float xq = 0.f, yq = 0.f, mq = 0.f;                                \
            if (wp != 0.f) heat_params(joint2d, b, jp, xp, yp, mp);            \
            if (wc != 0.f) heat_params(joint2d, b, jc, xq, yq, mq);            \
            const float col0 = (float)((4 * lane) & 63);                       \
            const float row0 = (float)(lane >> 4);                             \
            float cEp[4] = {0.f, 0.f, 0.f, 0.f};                               \
            float cEc[4] = {0.f, 0.f, 0.f, 0.f};                               \
            if (wp != 0.f) {                                                   \
                _Pragma("unroll")                                              \
                for (int q = 0; q < 4; ++q) {                                  \
                    const float dy = (col0 + (float)q) - yp;                   \
                    cEp[q] = __expf(-0.25f * dy * dy);                         \
                }                                                              \
            }                                                                  \
            if (wc != 0.f) {                                                   \
                _Pragma("unroll")                                              \
                for (int q = 0; q < 4; ++q) {                                  \
                    const float dy = (col0 + (float)q) - yq;                   \
                    cEc[q] = __expf(-0.25f * dy * dy);                         \
                }                                                              \
            }                                                                  \
            const float mp4 = 0.25f * mp;                                      \
            const float mq4 = 0.25f * mq;                                      \
            float acc = 0.f;                                                   \
            _Pragma("unroll")                                                  \
            for (int j = 0; j < 16; ++j) {                                     \
                const float fi = row0 + (float)(4 * j);                        \
                float rEp = 0.f, rEc = 0.f;                                    \
                if (wp != 0.f) {                                               \
                    const float dx = fi - xp;                                  \
                    rEp = __expf(fmaf(-0.25f * dx, dx, mp4));                  \
                }                                                              \
                if (wc != 0.f) {                                               \
                    const float dx = fi - xq;                                  \
                    rEc = __expf(fmaf(-0.25f * dx, dx, mq4));                  \
                }                                                              \
                const float mv[4] = {(buf)[j].x, (buf)[j].y,                   \
                                     (buf)[j].z, (buf)[j].w};                  \
                _Pragma("unroll")                                              \
                for (int q = 0; q < 4; ++q) {                                  \
                    const float tgt = fmaf(rEc, cEc[q], rEp * cEp[q]);         \
                    const float df = tgt - mv[q];                              \
                    acc = fmaf(df, df, acc);                                   \
                }                                                              \
            }                                                                  \
            acc = wave_reduce(acc);                                            \
            if (lane == 0) partial[b * PSTRIDE + c] = acc;                     \
            if (c == 0) {                                                      \
                float v = 0.f;                                                 \
                if (lane < NJ * 3) {                                           \
                    const int i = b * NJ * 3 + lane;                           \
                    v = fabsf(joints[i] - pred[i]);                            \
                }                                                              \
                v = wave_reduce(v);                                            \
                if (lane == 0) partial[b * PSTRIDE + 59] = v;                  \
            }                                                                  \
        }

    int sid = w;            // always < NS (2048 <= 15104)
    ISSUE(sid, bufA);
    while (true) {
        int nxt = sid + NWAVES;
        if (nxt < NS) ISSUE(nxt, bufB);
        PROCESS(sid, bufA);
        sid = nxt;
        if (sid >= NS) break;

        nxt = sid + NWAVES;
        if (nxt < NS) ISSUE(nxt, bufA);
        PROCESS(sid, bufB);
        sid = nxt;
        if (sid >= NS) break;
    }
    #undef ISSUE
    #undef PROCESS
}

// One block, 256 threads: thread b reduces batch row b (60 floats, 15 aligned
// float4 loads), then cross-thread double reduction. No atomics, no memset.
__global__ __launch_bounds__(256) void finalize_kernel(
    const float* __restrict__ partial,  // [B,PSTRIDE]
    float* __restrict__ out)            // [1]
{
    const int b = threadIdx.x;
    const float4* __restrict__ row = (const float4*)(partial + b * PSTRIDE);
    float4 r[15];
    #pragma unroll
    for (int i = 0; i < 15; ++i) r[i] = row[i];
    const float* pr = (const float*)r;

    float l2d = 0.f;
    #pragma unroll
    for (int c = 0; c < NJ; ++c) l2d += pr[c];

    float hem = 0.f;
    #pragma unroll
    for (int p = 0; p < NP; ++p) {
        const float n = sqrtf(pr[NJ + 3 * p + 0]) +
                        sqrtf(pr[NJ + 3 * p + 1]) +
                        sqrtf(pr[NJ + 3 * p + 2]);
        hem = fmaf(n, n, hem);
    }

    double v = ((double)pr[59] + 0.005 * ((double)l2d + (double)hem)) * (1.0 / BATCH);

    #pragma unroll
    for (int off = 32; off; off >>= 1) v += __shfl_down(v, off, 64);
    __shared__ double sh[4];
    if ((b & 63) == 0) sh[b >> 6] = v;
    __syncthreads();
    if (b == 0) out[0] = (float)(sh[0] + sh[1] + sh[2] + sh[3]);
}

extern "C" void kernel_launch(void* const* d_in, const int* in_sizes, int n_in,
                              void* d_out, int out_size, void* d_ws, size_t ws_size,
                              hipStream_t stream) {
    const float* pred    = (const float*)d_in[0];
    const float* joints  = (const float*)d_in[1];
    const float* middle  = (const float*)d_in[2];
    const float* joint2d = (const float*)d_in[3];
    float* out  = (float*)d_out;
    float* part = (float*)d_ws;   // BATCH*PSTRIDE floats, fully written before read

    slice_sum_kernel<<<NWAVES / 4, 256, 0, stream>>>(pred, joints, middle,
                                                     joint2d, part);
    finalize_kernel<<<1, 256, 0, stream>>>(part, out);
}